// Round 15
// baseline (1991.292 us; speedup 1.0000x reference)
//
#include <hip/hip_runtime.h>
#include <hip/hip_bf16.h>
#include <math.h>

#define T_STEPS 256
#define BATCH 64
#define DIN 256
#define DSTATE 512
#define NGATE 2048   // 4*DSTATE
#define NCLS 10000
#define NCLS_PAD 10112    // fallback f32 GEMM tiling (79*128)
#define NCLS_PAD2 10240   // fused-path B tiling (40*256)
#define ROWS 16384   // T_STEPS*BATCH
#define SCAN_BLOCKS 64
#define GROUP_BLOCKS 16
#define WORK_BLK 192
#define CHUNK_ROWS 4096
// bar layout (words): [0,1024) group flags | [1024,4096) worker flags |
// [4096,4160) pub counters | total 4352 zeroed by prep
#define BAR_WORDS 4352

typedef __attribute__((ext_vector_type(8))) short bf16x8;
typedef __attribute__((ext_vector_type(4))) float f32x4;

__device__ inline unsigned short f2b(float x) {
    __hip_bfloat16 h = __float2bfloat16(x);
    return *(unsigned short*)&h;
}
__device__ inline float b2f(unsigned short u) {
    return __uint_as_float(((unsigned int)u) << 16);
}

// ---- fused prep ----------------------------------------------------------
// [0,4096) Xb | [4096,8192) WhT | [8192,10240) WxT | [10240,10248) bias |
// [10248,10280) h0b | [10280,10297) bar(4352w) | [10297,11577) WoT (160x8)
__launch_bounds__(256)
__global__ void prep_all(const float* __restrict__ inputs, const float* __restrict__ Wx,
                         const float* __restrict__ Wh, const float* __restrict__ bias,
                         const float* __restrict__ h0, const float* __restrict__ Wo,
                         unsigned short* __restrict__ Xb, unsigned short* __restrict__ WxT,
                         unsigned short* __restrict__ WhT, float* __restrict__ bp,
                         unsigned short* __restrict__ h0b, unsigned* __restrict__ bar,
                         unsigned short* __restrict__ WoT) {
    __shared__ float tile[64][65];
    const int bid = blockIdx.x;
    const int tid = threadIdx.x;
    if (bid < 4096) {
        int i = bid * 256 + tid;
        float4 v = *(const float4*)&inputs[(size_t)i * 4];
        ushort4 o; o.x = f2b(v.x); o.y = f2b(v.y); o.z = f2b(v.z); o.w = f2b(v.w);
        *(ushort4*)&Xb[(size_t)i * 4] = o;
    } else if (bid < 8192) {
        int e = (bid - 4096) * 256 + tid;
        int jp = e >> 9, k = e & 511;
        int s = jp >> 2, g = jp & 3;
        WhT[e] = f2b(Wh[(size_t)k * NGATE + g * DSTATE + s]);
    } else if (bid < 10240) {
        int e = (bid - 8192) * 256 + tid;
        int jp = e >> 8, k = e & 255;
        int s = jp >> 2, g = jp & 3;
        WxT[e] = f2b(Wx[(size_t)k * NGATE + g * DSTATE + s]);
    } else if (bid < 10248) {
        int jp = (bid - 10240) * 256 + tid;
        if (jp < NGATE) bp[jp] = bias[(jp & 3) * DSTATE + (jp >> 2)];
    } else if (bid < 10280) {
        int i = (bid - 10248) * 256 + tid;
        if (i < BATCH * DSTATE / 4) {
            float4 v = *(const float4*)&h0[(size_t)i * 4];
            ushort4 o; o.x = f2b(v.x); o.y = f2b(v.y); o.z = f2b(v.z); o.w = f2b(v.w);
            *(ushort4*)&h0b[(size_t)i * 4] = o;
        }
    } else if (bid < 10297) {
        int i = (bid - 10280) * 256 + tid;
        if (i < BAR_WORDS) bar[i] = 0u;
    } else {
        int nb = bid - 10297;                 // 0..1279 (160 n x 8 k)
        int n0 = (nb % 160) * 64, k0 = (nb / 160) * 64;
        #pragma unroll
        for (int r = 0; r < 16; ++r) {
            int k = (tid >> 6) + r * 4;
            int n = tid & 63;
            float v = (n0 + n < NCLS) ? Wo[(size_t)(k0 + k) * NCLS + n0 + n] : 0.f;
            tile[k][n] = v;
        }
        __syncthreads();
        #pragma unroll
        for (int r = 0; r < 16; ++r) {
            int n = (tid >> 6) + r * 4;
            int k = tid & 63;
            WoT[(size_t)(n0 + n) * DSTATE + k0 + k] = f2b(tile[k][n]);
        }
    }
}

// ---- Zx = X @ Wx (+bias), output transposed (r9-verified) ----------------
__launch_bounds__(256)
__global__ void zx_gemm(const unsigned short* __restrict__ Xb,
                        const unsigned short* __restrict__ WxT,
                        const float* __restrict__ bp,
                        unsigned short* __restrict__ ZxT) {
    __shared__ unsigned short As[64][264];
    __shared__ unsigned short Bs[128][264];
    __shared__ float zls[4][32][65];
    const int tid = threadIdx.x;
    const int t = blockIdx.x;
    const int n0 = blockIdx.y * 128;
    const int wave = tid >> 6, lane = tid & 63, mr = lane & 15, g = lane >> 4;

    #pragma unroll
    for (int r = 0; r < 8; ++r) {
        int c = r * 256 + tid; int row = c >> 5, q = c & 31;
        *(int4*)&As[row][q * 8] = *(const int4*)&Xb[((size_t)t * 64 + row) * DIN + q * 8];
    }
    #pragma unroll
    for (int r = 0; r < 16; ++r) {
        int c = r * 256 + tid; int row = c >> 5, q = c & 31;
        *(int4*)&Bs[row][q * 8] = *(const int4*)&WxT[(size_t)(n0 + row) * DIN + q * 8];
    }
    __syncthreads();

    f32x4 acc[4][2] = {};
    #pragma unroll
    for (int kt = 0; kt < DIN; kt += 32) {
        bf16x8 af[4], bf[2];
        #pragma unroll
        for (int fm = 0; fm < 4; ++fm) af[fm] = *(const bf16x8*)&As[fm * 16 + mr][kt + g * 8];
        #pragma unroll
        for (int fn = 0; fn < 2; ++fn) bf[fn] = *(const bf16x8*)&Bs[wave * 32 + fn * 16 + mr][kt + g * 8];
        #pragma unroll
        for (int fm = 0; fm < 4; ++fm)
            #pragma unroll
            for (int fn = 0; fn < 2; ++fn)
                acc[fm][fn] = __builtin_amdgcn_mfma_f32_16x16x32_bf16(af[fm], bf[fn], acc[fm][fn], 0, 0, 0);
    }
    #pragma unroll
    for (int fm = 0; fm < 4; ++fm)
        #pragma unroll
        for (int fn = 0; fn < 2; ++fn)
            #pragma unroll
            for (int r = 0; r < 4; ++r)
                zls[wave][fn * 16 + mr][fm * 16 + g * 4 + r] = acc[fm][fn][r];
    #pragma unroll 4
    for (int jr = 0; jr < 32; ++jr) {
        int j = n0 + wave * 32 + jr;
        float v = zls[wave][jr][lane] + bp[j];
        ZxT[((size_t)t * NGATE + j) * 64 + lane] = f2b(v);
    }
}

// ---- distributed-flag GROUP barrier (r11-verified) -----------------------
__device__ __forceinline__ void groupbar(unsigned* fbase, int w, unsigned want, int tid) {
    __syncthreads();
    if (tid == 0)
        __hip_atomic_store(&fbase[w * 16], want, __ATOMIC_RELEASE, __HIP_MEMORY_SCOPE_AGENT);
    if (tid < GROUP_BLOCKS) {
        while (__hip_atomic_load(&fbase[tid * 16], __ATOMIC_RELAXED, __HIP_MEMORY_SCOPE_AGENT) < want) {}
        (void)__hip_atomic_load(&fbase[tid * 16], __ATOMIC_ACQUIRE, __HIP_MEMORY_SCOPE_AGENT);
    }
    __syncthreads();
}

// ---- distributed-flag WORKER barrier (192 participants) ------------------
__device__ __forceinline__ void workbar(unsigned* wfl, int wid, unsigned want, int tid) {
    __syncthreads();
    if (tid == 0)
        __hip_atomic_store(&wfl[wid * 16], want, __ATOMIC_RELEASE, __HIP_MEMORY_SCOPE_AGENT);
    if (tid < WORK_BLK) {
        while (__hip_atomic_load(&wfl[tid * 16], __ATOMIC_RELAXED, __HIP_MEMORY_SCOPE_AGENT) < want)
            __builtin_amdgcn_s_sleep(1);
        (void)__hip_atomic_load(&wfl[tid * 16], __ATOMIC_ACQUIRE, __HIP_MEMORY_SCOPE_AGENT);
    }
    __syncthreads();
}

__device__ inline float wave_reduce_max(float v) {
    #pragma unroll
    for (int off = 32; off > 0; off >>= 1) v = fmaxf(v, __shfl_xor(v, off));
    return v;
}
__device__ inline float wave_reduce_sum(float v) {
    #pragma unroll
    for (int off = 32; off > 0; off >>= 1) v += __shfl_xor(v, off);
    return v;
}

// ---- MEGA kernel: scan (blocks 0..63) + GEMM/softmax workers (64..255) ---
// Publication decoupled from per-step flags: pub[c] at bar+4096 (own lines,
// PAST the worker-flag region — r14's overlap bug fixed) gets one
// release-fetch_add per scan block per chunk; workers poll ONLY pub.
__launch_bounds__(512, 1)
__global__ void lstm_mega(const unsigned short* __restrict__ h0b,
                          const float* __restrict__ c0,
                          const unsigned short* __restrict__ WhT,
                          const unsigned short* __restrict__ ZxT,
                          unsigned short* __restrict__ hsb,
                          unsigned* __restrict__ bar,
                          const unsigned short* __restrict__ WoT,  // [10240][512]
                          const float* __restrict__ bo,
                          const float* __restrict__ labels,
                          unsigned short* __restrict__ Cb,         // [4096][NCLS]
                          float* __restrict__ probs,               // = out
                          float* __restrict__ rowloss) {
    __shared__ __align__(16) char smem[158208];
    const int tid = threadIdx.x;
    const int bid = blockIdx.x;
    unsigned* pub = bar + 4096;                 // 4 counters x 16-word stride

    if (bid < SCAN_BLOCKS) {
        // ================= scan role (r11 structure, 512-thread block) =====
        unsigned short (*Wl)[520] = (unsigned short(*)[520])smem;
        unsigned short (*hT)[520] = (unsigned short(*)[520])(smem + 133120);
        float (*zb)[132] = (float(*)[132])(smem + 149760);
        const int grp = bid >> 4, w = bid & 15;
        const int b0 = grp * 16, j0 = w * 128, s0 = w * 32;
        const int wave = tid >> 6, lane = tid & 63, mr = lane & 15, gl = lane >> 4;
        unsigned* fbase = bar + grp * 256;

        if (tid < 256) {
            #pragma unroll 4
            for (int r = 0; r < 32; ++r) {
                int c = r * 256 + tid; int row = c >> 6, q = c & 63;
                *(int4*)&Wl[row][q * 8] = *(const int4*)&WhT[(size_t)(j0 + row) * DSTATE + q * 8];
            }
        }
        const int gb  = lane >> 2;
        const int slg = wave * 8 + (lane & 3) * 2;
        float creg0 = 0.f, creg1 = 0.f;
        if (tid < 256) {
            creg0 = c0[(b0 + gb) * DSTATE + s0 + slg];
            creg1 = c0[(b0 + gb) * DSTATE + s0 + slg + 1];
        }
        __syncthreads();

        size_t zo0 = 0, zo1 = 0;
        ushort4 za0 = {0,0,0,0}, za1 = {0,0,0,0};
        if (tid < 256) {
            zo0 = ((size_t)(j0 + wave * 32 + mr)) * 64 + b0 + gl * 4;
            zo1 = ((size_t)(j0 + wave * 32 + 16 + mr)) * 64 + b0 + gl * 4;
            za0 = *(const ushort4*)&ZxT[zo0];
            za1 = *(const ushort4*)&ZxT[zo1];
        }

        for (int t = 0; t < T_STEPS; ++t) {
            // publish completed chunk (this block's stores for the chunk are
            // vmcnt-drained by the preceding groupbar; release orders them)
            if (t > 0 && (t & 63) == 0 && tid == 0)
                __hip_atomic_fetch_add(&pub[((t >> 6) - 1) * 16], 1u,
                                       __ATOMIC_RELEASE, __HIP_MEMORY_SCOPE_AGENT);
            const unsigned short* hsrc = t ? (hsb + (size_t)(t - 1) * BATCH * DSTATE) : h0b;
            if (tid < 256) {
                #pragma unroll
                for (int r = 0; r < 4; ++r) {
                    int c = r * 256 + tid; int row = c >> 6, q = c & 63;
                    *(int4*)&hT[row][q * 8] = *(const int4*)&hsrc[(size_t)(b0 + row) * DSTATE + q * 8];
                }
            }
            __syncthreads();
            if (tid < 256) {
                f32x4 acc0, acc1;
                acc0[0] = b2f(za0.x); acc0[1] = b2f(za0.y); acc0[2] = b2f(za0.z); acc0[3] = b2f(za0.w);
                acc1[0] = b2f(za1.x); acc1[1] = b2f(za1.y); acc1[2] = b2f(za1.z); acc1[3] = b2f(za1.w);
                if (t + 1 < T_STEPS) {
                    za0 = *(const ushort4*)&ZxT[(size_t)(t + 1) * NGATE * 64 + zo0];
                    za1 = *(const ushort4*)&ZxT[(size_t)(t + 1) * NGATE * 64 + zo1];
                }
                #pragma unroll
                for (int kt = 0; kt < DSTATE; kt += 32) {
                    bf16x8 af = *(const bf16x8*)&hT[mr][kt + gl * 8];
                    acc0 = __builtin_amdgcn_mfma_f32_16x16x32_bf16(af, *(const bf16x8*)&Wl[wave * 32 + mr][kt + gl * 8], acc0, 0, 0, 0);
                    acc1 = __builtin_amdgcn_mfma_f32_16x16x32_bf16(af, *(const bf16x8*)&Wl[wave * 32 + 16 + mr][kt + gl * 8], acc1, 0, 0, 0);
                }
                #pragma unroll
                for (int r = 0; r < 4; ++r) {
                    zb[gl * 4 + r][wave * 32 + mr] = acc0[r];
                    zb[gl * 4 + r][wave * 32 + 16 + mr] = acc1[r];
                }
                float zi0 = zb[gb][slg * 4 + 0], zf0 = zb[gb][slg * 4 + 1];
                float zg0 = zb[gb][slg * 4 + 2], zo0v = zb[gb][slg * 4 + 3];
                float zi1 = zb[gb][slg * 4 + 4], zf1 = zb[gb][slg * 4 + 5];
                float zg1 = zb[gb][slg * 4 + 6], zo1v = zb[gb][slg * 4 + 7];
                float i0 = 1.f / (1.f + expf(-zi0)), f0 = 1.f / (1.f + expf(-zf0));
                float o0 = 1.f / (1.f + expf(-zo0v)), g0 = tanhf(zg0);
                float i1 = 1.f / (1.f + expf(-zi1)), f1 = 1.f / (1.f + expf(-zf1));
                float o1 = 1.f / (1.f + expf(-zo1v)), g1 = tanhf(zg1);
                creg0 = f0 * creg0 + i0 * g0;
                creg1 = f1 * creg1 + i1 * g1;
                float h0v = o0 * tanhf(creg0);
                float h1v = o1 * tanhf(creg1);
                ushort2 hv; hv.x = f2b(h0v); hv.y = f2b(h1v);
                *(ushort2*)&hsb[((size_t)t * BATCH + b0 + gb) * DSTATE + s0 + slg] = hv;
            }
            if (t != T_STEPS - 1)
                groupbar(fbase, w, (unsigned)(t + 1), tid);
        }
        __syncthreads();   // drains final gate-phase stores (vmcnt) before release
        if (tid == 0)
            __hip_atomic_fetch_add(&pub[3 * 16], 1u,
                                   __ATOMIC_RELEASE, __HIP_MEMORY_SCOPE_AGENT);
        return;
    }

    // ================= worker role =========================================
    const int wid = bid - SCAN_BLOCKS;          // 0..191
    unsigned* wfl = bar + 1024;                 // worker flags [1024,4096)
    unsigned short* As = (unsigned short*)smem;                 //  8,192 B
    unsigned short* Bs = (unsigned short*)(smem + 8192);        // 16,384 B
    unsigned short (*sC)[264] = (unsigned short(*)[264])(smem + 24576); // 67,584 B
    float* rowf = (float*)smem;                 // 40,000 B (softmax phase)
    float* smr  = (float*)(smem + 40000);       // 8 floats
    const int wave = tid >> 6, lane = tid & 63, mr = lane & 15, g = lane >> 4;
    const int wm = wave >> 2, wn = wave & 3;

    for (int c4 = 0; c4 < 4; ++c4) {
        // ---- wait for chunk publication: ONE lane, ONE line, slow poll ----
        if (tid == 0) {
            while (__hip_atomic_load(&pub[c4 * 16], __ATOMIC_RELAXED, __HIP_MEMORY_SCOPE_AGENT) < (unsigned)SCAN_BLOCKS)
                __builtin_amdgcn_s_sleep(64);
            (void)__hip_atomic_load(&pub[c4 * 16], __ATOMIC_ACQUIRE, __HIP_MEMORY_SCOPE_AGENT);
        }
        __syncthreads();
        const unsigned short* A = hsb + (size_t)c4 * CHUNK_ROWS * DSTATE;

        // ---- GEMM: 128x256 tiles, 8 waves ----
        for (int tile = wid; tile < 32 * 40; tile += WORK_BLK) {
            const int m0 = (tile & 31) * 128;
            const int n0 = (tile >> 5) * 256;
            f32x4 acc[4][4] = {};
            for (int kt = 0; kt < DSTATE; kt += 32) {
                __builtin_amdgcn_global_load_lds(
                    (const __attribute__((address_space(1))) void*)&A[(size_t)(m0 + (tid >> 2)) * DSTATE + kt + (tid & 3) * 8],
                    (__attribute__((address_space(3))) void*)&As[tid * 8 - lane * 8], 16, 0, 0);
                __builtin_amdgcn_global_load_lds(
                    (const __attribute__((address_space(1))) void*)&WoT[(size_t)(n0 + (tid >> 2)) * DSTATE + kt + (tid & 3) * 8],
                    (__attribute__((address_space(3))) void*)&Bs[tid * 8 - lane * 8], 16, 0, 0);
                __builtin_amdgcn_global_load_lds(
                    (const __attribute__((address_space(1))) void*)&WoT[(size_t)(n0 + 128 + (tid >> 2)) * DSTATE + kt + (tid & 3) * 8],
                    (__attribute__((address_space(3))) void*)&Bs[4096 + tid * 8 - lane * 8], 16, 0, 0);
                __syncthreads();
                bf16x8 af[4], bf[4];
                #pragma unroll
                for (int f = 0; f < 4; ++f) {
                    af[f] = *(const bf16x8*)&As[(wm * 64 + f * 16 + mr) * 32 + g * 8];
                    bf[f] = *(const bf16x8*)&Bs[(wn * 64 + f * 16 + mr) * 32 + g * 8];
                }
                #pragma unroll
                for (int fm = 0; fm < 4; ++fm)
                    #pragma unroll
                    for (int fn = 0; fn < 4; ++fn)
                        acc[fm][fn] = __builtin_amdgcn_mfma_f32_16x16x32_bf16(af[fm], bf[fn], acc[fm][fn], 0, 0, 0);
                __syncthreads();
            }
            #pragma unroll
            for (int fn = 0; fn < 4; ++fn) {
                int colg = n0 + wn * 64 + fn * 16 + mr;
                float bias = (colg < NCLS) ? bo[colg] : 0.f;
                #pragma unroll
                for (int fm = 0; fm < 4; ++fm)
                    #pragma unroll
                    for (int r = 0; r < 4; ++r)
                        sC[wm * 64 + fm * 16 + g * 4 + r][wn * 64 + fn * 16 + mr] = f2b(acc[fm][fn][r] + bias);
            }
            __syncthreads();
            #pragma unroll
            for (int rr = 0; rr < 8; ++rr) {
                int row_l = (tid >> 5) + rr * 16;
                int col0 = (tid & 31) * 8;
                if (n0 + col0 < NCLS)
                    *(int4*)&Cb[(size_t)(m0 + row_l) * NCLS + n0 + col0] = *(int4*)&sC[row_l][col0];
            }
            __syncthreads();
        }
        workbar(wfl, wid, (unsigned)(2 * c4 + 1), tid);

        // ---- softmax rows of this chunk ----
        for (int r = wid; r < CHUNK_ROWS; r += WORK_BLK) {
            const size_t cbase = (size_t)r * NCLS;
            const size_t gbase = ((size_t)c4 * CHUNK_ROWS + r) * NCLS;
            float m = -INFINITY;
            for (int c8 = tid; c8 < NCLS / 8; c8 += 512) {
                ushort4 u0 = *(const ushort4*)&Cb[cbase + c8 * 8];
                ushort4 u1 = *(const ushort4*)&Cb[cbase + c8 * 8 + 4];
                float v0 = b2f(u0.x), v1 = b2f(u0.y), v2 = b2f(u0.z), v3 = b2f(u0.w);
                float v4 = b2f(u1.x), v5 = b2f(u1.y), v6 = b2f(u1.z), v7 = b2f(u1.w);
                float4 a = {v0, v1, v2, v3}, b = {v4, v5, v6, v7};
                *(float4*)&rowf[c8 * 8] = a;
                *(float4*)&rowf[c8 * 8 + 4] = b;
                m = fmaxf(m, fmaxf(fmaxf(fmaxf(v0, v1), fmaxf(v2, v3)),
                                   fmaxf(fmaxf(v4, v5), fmaxf(v6, v7))));
            }
            m = wave_reduce_max(m);
            if ((tid & 63) == 0) smr[tid >> 6] = m;
            __syncthreads();
            m = fmaxf(fmaxf(fmaxf(smr[0], smr[1]), fmaxf(smr[2], smr[3])),
                      fmaxf(fmaxf(smr[4], smr[5]), fmaxf(smr[6], smr[7])));
            __syncthreads();

            float s = 0.f, dot = 0.f;
            for (int q = tid; q < NCLS / 4; q += 512) {
                float4 v = *(const float4*)&rowf[q * 4];
                float4 lb = *(const float4*)&labels[gbase + q * 4];
                s += expf(v.x - m) + expf(v.y - m) + expf(v.z - m) + expf(v.w - m);
                dot += lb.x * v.x + lb.y * v.y + lb.z * v.z + lb.w * v.w;
            }
            s = wave_reduce_sum(s);
            if ((tid & 63) == 0) smr[tid >> 6] = s;
            __syncthreads();
            s = ((smr[0] + smr[1]) + (smr[2] + smr[3])) + ((smr[4] + smr[5]) + (smr[6] + smr[7]));
            __syncthreads();
            dot = wave_reduce_sum(dot);
            if ((tid & 63) == 0) smr[tid >> 6] = dot;
            __syncthreads();
            dot = ((smr[0] + smr[1]) + (smr[2] + smr[3])) + ((smr[4] + smr[5]) + (smr[6] + smr[7]));

            float inv = 1.f / s;
            for (int q = tid; q < NCLS / 4; q += 512) {
                float4 v = *(const float4*)&rowf[q * 4];
                float4 o;
                o.x = expf(v.x - m) * inv; o.y = expf(v.y - m) * inv;
                o.z = expf(v.z - m) * inv; o.w = expf(v.w - m) * inv;
                *(float4*)&probs[gbase + q * 4] = o;
            }
            if (tid == 0) rowloss[c4 * CHUNK_ROWS + r] = (m + logf(s)) - dot;
            __syncthreads();
        }
        if (c4 < 3) workbar(wfl, wid, (unsigned)(2 * c4 + 2), tid);
    }
}

// ---- FALLBACK kernels (r12-proven serial path) ---------------------------
__launch_bounds__(256, 1)
__global__ void lstm_scan_mfma(const unsigned short* __restrict__ h0b,
                               const float* __restrict__ c0,
                               const unsigned short* __restrict__ WhT,
                               const unsigned short* __restrict__ ZxT,
                               unsigned short* __restrict__ hsb,
                               unsigned* __restrict__ bar) {
    __shared__ unsigned short Wl[128][520];
    __shared__ unsigned short hT[16][520];
    __shared__ float zb[16][132];
    const int tid = threadIdx.x;
    const int bid = blockIdx.x;
    const int grp = bid >> 4, w = bid & 15;
    const int b0 = grp * 16, j0 = w * 128, s0 = w * 32;
    const int wave = tid >> 6, lane = tid & 63, mr = lane & 15, gl = lane >> 4;
    unsigned* fbase = bar + grp * 256;

    #pragma unroll 4
    for (int r = 0; r < 32; ++r) {
        int c = r * 256 + tid; int row = c >> 6, q = c & 63;
        *(int4*)&Wl[row][q * 8] = *(const int4*)&WhT[(size_t)(j0 + row) * DSTATE + q * 8];
    }
    const int gb = lane >> 2;
    const int slg = wave * 8 + (lane & 3) * 2;
    float creg0 = c0[(b0 + gb) * DSTATE + s0 + slg];
    float creg1 = c0[(b0 + gb) * DSTATE + s0 + slg + 1];
    __syncthreads();

    const size_t zo0 = ((size_t)(j0 + wave * 32 + mr)) * 64 + b0 + gl * 4;
    const size_t zo1 = ((size_t)(j0 + wave * 32 + 16 + mr)) * 64 + b0 + gl * 4;
    ushort4 za0 = *(const ushort4*)&ZxT[zo0];
    ushort4 za1 = *(const ushort4*)&ZxT[zo1];

    for (int t = 0; t < T_STEPS; ++t) {
        const unsigned short* hsrc = t ? (hsb + (size_t)(t - 1) * BATCH * DSTATE) : h0b;
        #pragma unroll
        for (int r = 0; r < 4; ++r) {
            int c = r * 256 + tid; int row = c >> 6, q = c & 63;
            *(int4*)&hT[row][q * 8] = *(const int4*)&hsrc[(size_t)(b0 + row) * DSTATE + q * 8];
        }
        __syncthreads();
        f32x4 acc0, acc1;
        acc0[0] = b2f(za0.x); acc0[1] = b2f(za0.y); acc0[2] = b2f(za0.z); acc0[3] = b2f(za0.w);
        acc1[0] = b2f(za1.x); acc1[1] = b2f(za1.y); acc1[2] = b2f(za1.z); acc1[3] = b2f(za1.w);
        if (t + 1 < T_STEPS) {
            za0 = *(const ushort4*)&ZxT[(size_t)(t + 1) * NGATE * 64 + zo0];
            za1 = *(const ushort4*)&ZxT[(size_t)(t + 1) * NGATE * 64 + zo1];
        }
        #pragma unroll
        for (int kt = 0; kt < DSTATE; kt += 32) {
            bf16x8 af = *(const bf16x8*)&hT[mr][kt + gl * 8];
            acc0 = __builtin_amdgcn_mfma_f32_16x16x32_bf16(af, *(const bf16x8*)&Wl[wave * 32 + mr][kt + gl * 8], acc0, 0, 0, 0);
            acc1 = __builtin_amdgcn_mfma_f32_16x16x32_bf16(af, *(const bf16x8*)&Wl[wave * 32 + 16 + mr][kt + gl * 8], acc1, 0, 0, 0);
        }
        #pragma unroll
        for (int r = 0; r < 4; ++r) {
            zb[gl * 4 + r][wave * 32 + mr] = acc0[r];
            zb[gl * 4 + r][wave * 32 + 16 + mr] = acc1[r];
        }
        {
            float zi0 = zb[gb][slg * 4 + 0], zf0 = zb[gb][slg * 4 + 1];
            float zg0 = zb[gb][slg * 4 + 2], zo0v = zb[gb][slg * 4 + 3];
            float zi1 = zb[gb][slg * 4 + 4], zf1 = zb[gb][slg * 4 + 5];
            float zg1 = zb[gb][slg * 4 + 6], zo1v = zb[gb][slg * 4 + 7];
            float i0 = 1.f / (1.f + expf(-zi0)), f0 = 1.f / (1.f + expf(-zf0));
            float o0 = 1.f / (1.f + expf(-zo0v)), g0 = tanhf(zg0);
            float i1 = 1.f / (1.f + expf(-zi1)), f1 = 1.f / (1.f + expf(-zf1));
            float o1 = 1.f / (1.f + expf(-zo1v)), g1 = tanhf(zg1);
            creg0 = f0 * creg0 + i0 * g0;
            creg1 = f1 * creg1 + i1 * g1;
            float h0v = o0 * tanhf(creg0);
            float h1v = o1 * tanhf(creg1);
            ushort2 hv; hv.x = f2b(h0v); hv.y = f2b(h1v);
            *(ushort2*)&hsb[((size_t)t * BATCH + b0 + gb) * DSTATE + s0 + slg] = hv;
        }
        if (t != T_STEPS - 1)
            groupbar(fbase, w, (unsigned)(t + 1), tid);
    }
}

__launch_bounds__(256)
__global__ void gemm_logits_mfma(const unsigned short* __restrict__ A,
                                 const unsigned short* __restrict__ Bt,
                                 const float* __restrict__ bo,
                                 float* __restrict__ C) {
    __shared__ unsigned short As[128 * 32];
    __shared__ unsigned short Bs[128 * 32];
    const int tid = threadIdx.x;
    const int wave = tid >> 6, lane = tid & 63;
    const int wm = wave >> 1, wn = wave & 1;
    const int m0 = blockIdx.y * 128, n0 = blockIdx.x * 128;
    const int g = lane >> 4, mr = lane & 15;
    const int ch0 = wave * 64 + lane;
    const int ch1 = (4 + wave) * 64 + lane;
    const int row0 = ch0 >> 2, q0 = ch0 & 3;
    const int row1 = ch1 >> 2, q1 = ch1 & 3;

    f32x4 acc[4][4] = {};
    for (int kt = 0; kt < DSTATE; kt += 32) {
        __builtin_amdgcn_global_load_lds(
            (const __attribute__((address_space(1))) void*)&A[(size_t)(m0 + row0) * DSTATE + kt + q0 * 8],
            (__attribute__((address_space(3))) void*)&As[ch0 * 8 - lane * 8], 16, 0, 0);
        __builtin_amdgcn_global_load_lds(
            (const __attribute__((address_space(1))) void*)&A[(size_t)(m0 + row1) * DSTATE + kt + q1 * 8],
            (__attribute__((address_space(3))) void*)&As[ch1 * 8 - lane * 8], 16, 0, 0);
        __builtin_amdgcn_global_load_lds(
            (const __attribute__((address_space(1))) void*)&Bt[(size_t)(n0 + row0) * DSTATE + kt + q0 * 8],
            (__attribute__((address_space(3))) void*)&Bs[ch0 * 8 - lane * 8], 16, 0, 0);
        __builtin_amdgcn_global_load_lds(
            (const __attribute__((address_space(1))) void*)&Bt[(size_t)(n0 + row1) * DSTATE + kt + q1 * 8],
            (__attribute__((address_space(3))) void*)&Bs[ch1 * 8 - lane * 8], 16, 0, 0);
        __syncthreads();
        bf16x8 af[4], bf[4];
        #pragma unroll
        for (int f = 0; f < 4; ++f) {
            af[f] = *(const bf16x8*)&As[(wm * 64 + f * 16 + mr) * 32 + g * 8];
            bf[f] = *(const bf16x8*)&Bs[(wn * 64 + f * 16 + mr) * 32 + g * 8];
        }
        #pragma unroll
        for (int fm = 0; fm < 4; ++fm)
            #pragma unroll
            for (int fn = 0; fn < 4; ++fn)
                acc[fm][fn] = __builtin_amdgcn_mfma_f32_16x16x32_bf16(af[fm], bf[fn], acc[fm][fn], 0, 0, 0);
        __syncthreads();
    }
    #pragma unroll
    for (int fm = 0; fm < 4; ++fm) {
        #pragma unroll
        for (int fn = 0; fn < 4; ++fn) {
            int col = n0 + wn * 64 + fn * 16 + mr;
            if (col >= NCLS) continue;
            float bias = bo[col];
            #pragma unroll
            for (int r = 0; r < 4; ++r) {
                int row = m0 + wm * 64 + fm * 16 + g * 4 + r;
                C[(size_t)row * NCLS + col] = acc[fm][fn][r] + bias;
            }
        }
    }
}

__launch_bounds__(256)
__global__ void softmax_loss(float* __restrict__ logits,
                             const float* __restrict__ labels,
                             float* __restrict__ rowloss) {
    __shared__ float row[NCLS];
    __shared__ float sm[4];
    const int tid = threadIdx.x;
    const size_t base = (size_t)blockIdx.x * NCLS;

    float m = -INFINITY;
    for (int c4 = tid; c4 < NCLS / 4; c4 += 256) {
        float4 v = *(const float4*)&logits[base + c4 * 4];
        *(float4*)&row[c4 * 4] = v;
        m = fmaxf(fmaxf(m, fmaxf(v.x, v.y)), fmaxf(v.z, v.w));
    }
    m = wave_reduce_max(m);
    if ((tid & 63) == 0) sm[tid >> 6] = m;
    __syncthreads();
    m = fmaxf(fmaxf(sm[0], sm[1]), fmaxf(sm[2], sm[3]));
    __syncthreads();

    float s = 0.f, dot = 0.f;
    for (int c4 = tid; c4 < NCLS / 4; c4 += 256) {
        float4 v = *(const float4*)&row[c4 * 4];
        float4 lb = *(const float4*)&labels[base + c4 * 4];
        s += expf(v.x - m) + expf(v.y - m) + expf(v.z - m) + expf(v.w - m);
        dot += lb.x * v.x + lb.y * v.y + lb.z * v.z + lb.w * v.w;
    }
    s = wave_reduce_sum(s);
    if ((tid & 63) == 0) sm[tid >> 6] = s;
    __syncthreads();
    s = sm[0] + sm[1] + sm[2] + sm[3];
    __syncthreads();
    dot = wave_reduce_sum(dot);
    if ((tid & 63) == 0) sm[tid >> 6] = dot;
    __syncthreads();
    dot = sm[0] + sm[1] + sm[2] + sm[3];

    float inv = 1.f / s;
    for (int c4 = tid; c4 < NCLS / 4; c4 += 256) {
        float4 v = *(const float4*)&row[c4 * 4];
        float4 o;
        o.x = expf(v.x - m) * inv; o.y = expf(v.y - m) * inv;
        o.z = expf(v.z - m) * inv; o.w = expf(v.w - m) * inv;
        *(float4*)&logits[base + c4 * 4] = o;
    }
    if (tid == 0) rowloss[blockIdx.x] = (m + logf(s)) - dot;
}

__launch_bounds__(256)
__global__ void loss_reduce(const float* __restrict__ rowloss, float* __restrict__ out) {
    __shared__ float sm[4];
    float s = 0.f;
    for (int i = threadIdx.x; i < ROWS; i += 256) s += rowloss[i];
    s = wave_reduce_sum(s);
    if ((threadIdx.x & 63) == 0) sm[threadIdx.x >> 6] = s;
    __syncthreads();
    if (threadIdx.x == 0) out[0] = (sm[0] + sm[1] + sm[2] + sm[3]) * (1.f / ROWS);
}

// ---- launcher ------------------------------------------------------------
extern "C" void kernel_launch(void* const* d_in, const int* in_sizes, int n_in,
                              void* d_out, int out_size, void* d_ws, size_t ws_size,
                              hipStream_t stream) {
    const float* inputs = (const float*)d_in[0];
    const float* labels = (const float*)d_in[1];
    const float* c0     = (const float*)d_in[2];
    const float* h0     = (const float*)d_in[3];
    const float* Wx     = (const float*)d_in[4];
    const float* Wh     = (const float*)d_in[5];
    const float* bias   = (const float*)d_in[6];
    const float* Wo     = (const float*)d_in[7];
    const float* bo     = (const float*)d_in[8];
    float* out = (float*)d_out;

    float* ws = (float*)d_ws;
    float* bp       = ws;                                      // 2048 f32
    float* rowloss  = bp + 2048;                               // 16384 f32
    unsigned short* WhT = (unsigned short*)(rowloss + 16384);  // 2048*512
    unsigned short* WxT = WhT + 1048576;                       // 2048*256
    unsigned short* Xb  = WxT + 524288;                        // 16384*256
    unsigned short* h0b = Xb + 4194304;                        // 64*512
    unsigned short* hsb = h0b + 32768;                         // 16384*512
    unsigned short* WoT = hsb + 8388608;                       // 10240*512
    unsigned short* ZxT = WoT + 5242880;                       // 256*2048*64
    unsigned* bar = (unsigned*)(ZxT + 33554432);               // BAR_WORDS words
    unsigned short* Cb = (unsigned short*)(bar + BAR_WORDS);   // 4096*10000 bf16

    size_t base_bytes = (size_t)((char*)Cb - (char*)d_ws);
    size_t need_fused = base_bytes + (size_t)CHUNK_ROWS * NCLS * sizeof(unsigned short);
    bool use_fused = (ws_size >= need_fused);

    prep_all<<<11577, 256, 0, stream>>>(inputs, Wx, Wh, bias, h0, Wo,
                                        Xb, WxT, WhT, bp, h0b, bar, WoT);

    zx_gemm<<<dim3(T_STEPS, NGATE / 128), 256, 0, stream>>>(Xb, WxT, bp, ZxT);

    if (use_fused) {
        void* args[] = {(void*)&h0b, (void*)&c0, (void*)&WhT, (void*)&ZxT, (void*)&hsb,
                        (void*)&bar, (void*)&WoT, (void*)&bo, (void*)&labels,
                        (void*)&Cb, (void*)&out, (void*)&rowloss};
        hipLaunchCooperativeKernel((const void*)lstm_mega, dim3(SCAN_BLOCKS + WORK_BLK),
                                   dim3(512), args, 0, stream);
    } else {
        void* args[] = {(void*)&h0b, (void*)&c0, (void*)&WhT, (void*)&ZxT, (void*)&hsb, (void*)&bar};
        hipLaunchCooperativeKernel((const void*)lstm_scan_mfma, dim3(SCAN_BLOCKS),
                                   dim3(256), args, 0, stream);
        gemm_logits_mfma<<<dim3(NCLS_PAD / 128, ROWS / 128), 256, 0, stream>>>(hsb, WoT, bo, out);
        softmax_loss<<<ROWS, 256, 0, stream>>>(out, labels, rowloss);
    }
    loss_reduce<<<1, 256, 0, stream>>>(rowloss, out + (size_t)ROWS * NCLS);
}

// Round 16
// 1891.662 us; speedup vs baseline: 1.0527x; 1.0527x over previous
//
#include <hip/hip_runtime.h>
#include <hip/hip_bf16.h>
#include <math.h>

#define T_STEPS 256
#define BATCH 64
#define DIN 256
#define DSTATE 512
#define NGATE 2048   // 4*DSTATE
#define NCLS 10000
#define NCLS_PAD 10112   // 79 * 128
#define ROWS 16384   // T_STEPS*BATCH
#define SCAN_BLOCKS 64
#define GROUP_BLOCKS 16  // blocks per batch-group (barrier scope)
#define CHUNK_ROWS 4096  // rows per logits/softmax chunk (bf16 path)

typedef __attribute__((ext_vector_type(8))) short bf16x8;
typedef __attribute__((ext_vector_type(4))) float f32x4;

__device__ inline unsigned short f2b(float x) {
    __hip_bfloat16 h = __float2bfloat16(x);
    return *(unsigned short*)&h;
}
__device__ inline float b2f(unsigned short u) {
    return __uint_as_float(((unsigned int)u) << 16);
}

// ---- fused prep: all independent format conversions in ONE launch --------
// sections: [0,4096) inputs->bf16 | [4096,8192) WhT | [8192,10240) WxT |
// [10240,10248) bias | [10248,10280) h0->bf16 | [10280,10284) bar |
// [10284,11548) WoT transpose
__launch_bounds__(256)
__global__ void prep_all(const float* __restrict__ inputs, const float* __restrict__ Wx,
                         const float* __restrict__ Wh, const float* __restrict__ bias,
                         const float* __restrict__ h0, const float* __restrict__ Wo,
                         unsigned short* __restrict__ Xb, unsigned short* __restrict__ WxT,
                         unsigned short* __restrict__ WhT, float* __restrict__ bp,
                         unsigned short* __restrict__ h0b, unsigned* __restrict__ bar,
                         unsigned short* __restrict__ WoT) {
    __shared__ float tile[64][65];
    const int bid = blockIdx.x;
    const int tid = threadIdx.x;
    if (bid < 4096) {                         // inputs -> bf16 (float4 quads)
        int i = bid * 256 + tid;
        float4 v = *(const float4*)&inputs[(size_t)i * 4];
        ushort4 o; o.x = f2b(v.x); o.y = f2b(v.y); o.z = f2b(v.z); o.w = f2b(v.w);
        *(ushort4*)&Xb[(size_t)i * 4] = o;
    } else if (bid < 8192) {                  // WhT: permute+transpose+cvt
        int e = (bid - 4096) * 256 + tid;
        int jp = e >> 9, k = e & 511;
        int s = jp >> 2, g = jp & 3;
        WhT[e] = f2b(Wh[(size_t)k * NGATE + g * DSTATE + s]);
    } else if (bid < 10240) {                 // WxT
        int e = (bid - 8192) * 256 + tid;
        int jp = e >> 8, k = e & 255;
        int s = jp >> 2, g = jp & 3;
        WxT[e] = f2b(Wx[(size_t)k * NGATE + g * DSTATE + s]);
    } else if (bid < 10248) {                 // bias permute
        int jp = (bid - 10240) * 256 + tid;
        if (jp < NGATE) bp[jp] = bias[(jp & 3) * DSTATE + (jp >> 2)];
    } else if (bid < 10280) {                 // h0 -> bf16
        int i = (bid - 10248) * 256 + tid;
        if (i < BATCH * DSTATE / 4) {
            float4 v = *(const float4*)&h0[(size_t)i * 4];
            ushort4 o; o.x = f2b(v.x); o.y = f2b(v.y); o.z = f2b(v.z); o.w = f2b(v.w);
            *(ushort4*)&h0b[(size_t)i * 4] = o;
        }
    } else if (bid < 10284) {                 // barrier words (1024)
        bar[(bid - 10280) * 256 + tid] = 0u;
    } else {                                  // WoT tiled transpose + cvt
        int nb = bid - 10284;                 // 0..1263  (158 x 8)
        int n0 = (nb % 158) * 64, k0 = (nb / 158) * 64;
        #pragma unroll
        for (int r = 0; r < 16; ++r) {
            int k = (tid >> 6) + r * 4;
            int n = tid & 63;
            float v = (n0 + n < NCLS) ? Wo[(size_t)(k0 + k) * NCLS + n0 + n] : 0.f;
            tile[k][n] = v;
        }
        __syncthreads();
        #pragma unroll
        for (int r = 0; r < 16; ++r) {
            int n = (tid >> 6) + r * 4;
            int k = tid & 63;
            WoT[(size_t)(n0 + n) * DSTATE + k0 + k] = f2b(tile[k][n]);
        }
    }
}

// ---- Zx = X @ Wx (+bias), output transposed: ZxT[t][jp][b] bf16 ---------
__launch_bounds__(256)
__global__ void zx_gemm(const unsigned short* __restrict__ Xb,   // [16384][256]
                        const unsigned short* __restrict__ WxT,  // [2048][256]
                        const float* __restrict__ bp,            // [2048]
                        unsigned short* __restrict__ ZxT) {      // [256][2048][64]
    __shared__ unsigned short As[64][264];
    __shared__ unsigned short Bs[128][264];
    __shared__ float zls[4][32][65];
    const int tid = threadIdx.x;
    const int t = blockIdx.x;
    const int n0 = blockIdx.y * 128;
    const int wave = tid >> 6, lane = tid & 63, mr = lane & 15, g = lane >> 4;

    #pragma unroll
    for (int r = 0; r < 8; ++r) {
        int c = r * 256 + tid; int row = c >> 5, q = c & 31;
        *(int4*)&As[row][q * 8] = *(const int4*)&Xb[((size_t)t * 64 + row) * DIN + q * 8];
    }
    #pragma unroll
    for (int r = 0; r < 16; ++r) {
        int c = r * 256 + tid; int row = c >> 5, q = c & 31;
        *(int4*)&Bs[row][q * 8] = *(const int4*)&WxT[(size_t)(n0 + row) * DIN + q * 8];
    }
    __syncthreads();

    f32x4 acc[4][2] = {};
    #pragma unroll
    for (int kt = 0; kt < DIN; kt += 32) {
        bf16x8 af[4], bf[2];
        #pragma unroll
        for (int fm = 0; fm < 4; ++fm) af[fm] = *(const bf16x8*)&As[fm * 16 + mr][kt + g * 8];
        #pragma unroll
        for (int fn = 0; fn < 2; ++fn) bf[fn] = *(const bf16x8*)&Bs[wave * 32 + fn * 16 + mr][kt + g * 8];
        #pragma unroll
        for (int fm = 0; fm < 4; ++fm)
            #pragma unroll
            for (int fn = 0; fn < 2; ++fn)
                acc[fm][fn] = __builtin_amdgcn_mfma_f32_16x16x32_bf16(af[fm], bf[fn], acc[fm][fn], 0, 0, 0);
    }
    #pragma unroll
    for (int fm = 0; fm < 4; ++fm)
        #pragma unroll
        for (int fn = 0; fn < 2; ++fn)
            #pragma unroll
            for (int r = 0; r < 4; ++r)
                zls[wave][fn * 16 + mr][fm * 16 + g * 4 + r] = acc[fm][fn][r];
    #pragma unroll 4
    for (int jr = 0; jr < 32; ++jr) {
        int j = n0 + wave * 32 + jr;
        float v = zls[wave][jr][lane] + bp[j];
        ZxT[((size_t)t * NGATE + j) * 64 + lane] = f2b(v);
    }
}

// ---- distributed-flag GROUP barrier (r11-verified) -----------------------
__device__ __forceinline__ void groupbar(unsigned* fbase, int w, unsigned want, int tid) {
    __syncthreads();   // drains vmcnt: all h-stores of this block are complete
    if (tid == 0)
        __hip_atomic_store(&fbase[w * 16], want, __ATOMIC_RELEASE, __HIP_MEMORY_SCOPE_AGENT);
    if (tid < GROUP_BLOCKS) {
        while (__hip_atomic_load(&fbase[tid * 16], __ATOMIC_RELAXED, __HIP_MEMORY_SCOPE_AGENT) < want) {}
        (void)__hip_atomic_load(&fbase[tid * 16], __ATOMIC_ACQUIRE, __HIP_MEMORY_SCOPE_AGENT);
    }
    __syncthreads();
}

// ---- cooperative LSTM scan, batch-grouped: 4 groups x 16 blocks (r11) ----
__launch_bounds__(256, 1)
__global__ void lstm_scan_mfma(const unsigned short* __restrict__ h0b,  // [64][512] bf16
                               const float* __restrict__ c0,            // [64][512] f32
                               const unsigned short* __restrict__ WhT,  // [2048][512] bf16
                               const unsigned short* __restrict__ ZxT,  // [256][2048][64] bf16
                               unsigned short* __restrict__ hsb,        // [256][64][512] bf16
                               unsigned* __restrict__ bar) {
    __shared__ unsigned short Wl[128][520];  // 133,120 B
    __shared__ unsigned short hT[16][520];   //  16,640 B
    __shared__ float zb[16][132];            //   8,448 B
    const int tid = threadIdx.x;
    const int bid = blockIdx.x;
    const int grp = bid >> 4;
    const int w   = bid & 15;
    const int b0  = grp * 16;
    const int j0  = w * 128;
    const int s0  = w * 32;
    const int wave = tid >> 6, lane = tid & 63, mr = lane & 15, gl = lane >> 4;
    unsigned* fbase = bar + grp * 256;   // 16 flags x 16-word stride

    #pragma unroll 4
    for (int r = 0; r < 32; ++r) {
        int c = r * 256 + tid; int row = c >> 6, q = c & 63;
        *(int4*)&Wl[row][q * 8] = *(const int4*)&WhT[(size_t)(j0 + row) * DSTATE + q * 8];
    }

    const int gb  = lane >> 2;
    const int slg = wave * 8 + (lane & 3) * 2;
    float creg0 = c0[(b0 + gb) * DSTATE + s0 + slg];
    float creg1 = c0[(b0 + gb) * DSTATE + s0 + slg + 1];
    __syncthreads();

    const size_t zo0 = ((size_t)(j0 + wave * 32 + mr)) * 64 + b0 + gl * 4;
    const size_t zo1 = ((size_t)(j0 + wave * 32 + 16 + mr)) * 64 + b0 + gl * 4;
    ushort4 za0 = *(const ushort4*)&ZxT[zo0];
    ushort4 za1 = *(const ushort4*)&ZxT[zo1];

    for (int t = 0; t < T_STEPS; ++t) {
        const unsigned short* hsrc = t ? (hsb + (size_t)(t - 1) * BATCH * DSTATE) : h0b;
        #pragma unroll
        for (int r = 0; r < 4; ++r) {
            int c = r * 256 + tid; int row = c >> 6, q = c & 63;
            *(int4*)&hT[row][q * 8] = *(const int4*)&hsrc[(size_t)(b0 + row) * DSTATE + q * 8];
        }
        __syncthreads();

        f32x4 acc0, acc1;
        acc0[0] = b2f(za0.x); acc0[1] = b2f(za0.y); acc0[2] = b2f(za0.z); acc0[3] = b2f(za0.w);
        acc1[0] = b2f(za1.x); acc1[1] = b2f(za1.y); acc1[2] = b2f(za1.z); acc1[3] = b2f(za1.w);
        if (t + 1 < T_STEPS) {
            za0 = *(const ushort4*)&ZxT[(size_t)(t + 1) * NGATE * 64 + zo0];
            za1 = *(const ushort4*)&ZxT[(size_t)(t + 1) * NGATE * 64 + zo1];
        }
        #pragma unroll
        for (int kt = 0; kt < DSTATE; kt += 32) {
            bf16x8 af = *(const bf16x8*)&hT[mr][kt + gl * 8];
            acc0 = __builtin_amdgcn_mfma_f32_16x16x32_bf16(af, *(const bf16x8*)&Wl[wave * 32 + mr][kt + gl * 8], acc0, 0, 0, 0);
            acc1 = __builtin_amdgcn_mfma_f32_16x16x32_bf16(af, *(const bf16x8*)&Wl[wave * 32 + 16 + mr][kt + gl * 8], acc1, 0, 0, 0);
        }
        #pragma unroll
        for (int r = 0; r < 4; ++r) {
            zb[gl * 4 + r][wave * 32 + mr] = acc0[r];
            zb[gl * 4 + r][wave * 32 + 16 + mr] = acc1[r];
        }
        {
            float zi0 = zb[gb][slg * 4 + 0], zf0 = zb[gb][slg * 4 + 1];
            float zg0 = zb[gb][slg * 4 + 2], zo0v = zb[gb][slg * 4 + 3];
            float zi1 = zb[gb][slg * 4 + 4], zf1 = zb[gb][slg * 4 + 5];
            float zg1 = zb[gb][slg * 4 + 6], zo1v = zb[gb][slg * 4 + 7];
            float i0 = 1.f / (1.f + expf(-zi0)), f0 = 1.f / (1.f + expf(-zf0));
            float o0 = 1.f / (1.f + expf(-zo0v)), g0 = tanhf(zg0);
            float i1 = 1.f / (1.f + expf(-zi1)), f1 = 1.f / (1.f + expf(-zf1));
            float o1 = 1.f / (1.f + expf(-zo1v)), g1 = tanhf(zg1);
            creg0 = f0 * creg0 + i0 * g0;
            creg1 = f1 * creg1 + i1 * g1;
            float h0v = o0 * tanhf(creg0);
            float h1v = o1 * tanhf(creg1);
            ushort2 hv; hv.x = f2b(h0v); hv.y = f2b(h1v);
            *(ushort2*)&hsb[((size_t)t * BATCH + b0 + gb) * DSTATE + s0 + slg] = hv;
        }
        if (t != T_STEPS - 1)
            groupbar(fbase, w, (unsigned)(t + 1), tid);
    }
}

// ---- logits GEMM, bf16 C via LDS-coalesced epilogue (chunked path) -------
__launch_bounds__(256)
__global__ void gemm_logits_bf16(const unsigned short* __restrict__ A,   // [chunk_rows][512]
                                 const unsigned short* __restrict__ Bt,  // [NCLS_PAD][512]
                                 const float* __restrict__ bo,
                                 unsigned short* __restrict__ Cb) {      // [chunk_rows][NCLS]
    __shared__ unsigned short As[128 * 32];
    __shared__ unsigned short Bs[128 * 32];
    __shared__ unsigned short sC[128][136];   // 16B-aligned rows (272 B stride)
    const int tid = threadIdx.x;
    const int wave = tid >> 6, lane = tid & 63;
    const int wm = wave >> 1, wn = wave & 1;
    const int m0 = blockIdx.y * 128, n0 = blockIdx.x * 128;
    const int g = lane >> 4, mr = lane & 15;

    const int ch0 = wave * 64 + lane;
    const int ch1 = (4 + wave) * 64 + lane;
    const int row0 = ch0 >> 2, q0 = ch0 & 3;
    const int row1 = ch1 >> 2, q1 = ch1 & 3;

    f32x4 acc[4][4] = {};
    for (int kt = 0; kt < DSTATE; kt += 32) {
        __builtin_amdgcn_global_load_lds(
            (const __attribute__((address_space(1))) void*)&A[(size_t)(m0 + row0) * DSTATE + kt + q0 * 8],
            (__attribute__((address_space(3))) void*)&As[ch0 * 8 - lane * 8], 16, 0, 0);
        __builtin_amdgcn_global_load_lds(
            (const __attribute__((address_space(1))) void*)&A[(size_t)(m0 + row1) * DSTATE + kt + q1 * 8],
            (__attribute__((address_space(3))) void*)&As[ch1 * 8 - lane * 8], 16, 0, 0);
        __builtin_amdgcn_global_load_lds(
            (const __attribute__((address_space(1))) void*)&Bt[(size_t)(n0 + row0) * DSTATE + kt + q0 * 8],
            (__attribute__((address_space(3))) void*)&Bs[ch0 * 8 - lane * 8], 16, 0, 0);
        __builtin_amdgcn_global_load_lds(
            (const __attribute__((address_space(1))) void*)&Bt[(size_t)(n0 + row1) * DSTATE + kt + q1 * 8],
            (__attribute__((address_space(3))) void*)&Bs[ch1 * 8 - lane * 8], 16, 0, 0);
        __syncthreads();

        bf16x8 af[4], bf[4];
        #pragma unroll
        for (int f = 0; f < 4; ++f) {
            af[f] = *(const bf16x8*)&As[(wm * 64 + f * 16 + mr) * 32 + g * 8];
            bf[f] = *(const bf16x8*)&Bs[(wn * 64 + f * 16 + mr) * 32 + g * 8];
        }
        #pragma unroll
        for (int fm = 0; fm < 4; ++fm)
            #pragma unroll
            for (int fn = 0; fn < 4; ++fn)
                acc[fm][fn] = __builtin_amdgcn_mfma_f32_16x16x32_bf16(af[fm], bf[fn], acc[fm][fn], 0, 0, 0);
        __syncthreads();
    }
    // epilogue: bias + cvt into LDS tile, then fully-coalesced 16B row-chunk writes
    #pragma unroll
    for (int fn = 0; fn < 4; ++fn) {
        int colg = n0 + wn * 64 + fn * 16 + mr;
        float bias = (colg < NCLS) ? bo[colg] : 0.f;
        #pragma unroll
        for (int fm = 0; fm < 4; ++fm)
            #pragma unroll
            for (int r = 0; r < 4; ++r)
                sC[wm * 64 + fm * 16 + g * 4 + r][wn * 64 + fn * 16 + mr] = f2b(acc[fm][fn][r] + bias);
    }
    __syncthreads();
    #pragma unroll
    for (int rr = 0; rr < 8; ++rr) {
        int row_l = (tid >> 4) + rr * 16;
        int col0 = (tid & 15) * 8;
        int gcol = n0 + col0;
        if (gcol < NCLS)   // NCLS % 8 == 0 -> whole chunk valid iff start valid
            *(int4*)&Cb[(size_t)(m0 + row_l) * NCLS + gcol] = *(int4*)&sC[row_l][col0];
    }
}

// ---- logits GEMM, f32 C (fallback path) ----------------------------------
__launch_bounds__(256)
__global__ void gemm_logits_mfma(const unsigned short* __restrict__ A,
                                 const unsigned short* __restrict__ Bt,
                                 const float* __restrict__ bo,
                                 float* __restrict__ C) {
    __shared__ unsigned short As[128 * 32];
    __shared__ unsigned short Bs[128 * 32];
    const int tid = threadIdx.x;
    const int wave = tid >> 6, lane = tid & 63;
    const int wm = wave >> 1, wn = wave & 1;
    const int m0 = blockIdx.y * 128, n0 = blockIdx.x * 128;
    const int g = lane >> 4, mr = lane & 15;

    const int ch0 = wave * 64 + lane;
    const int ch1 = (4 + wave) * 64 + lane;
    const int row0 = ch0 >> 2, q0 = ch0 & 3;
    const int row1 = ch1 >> 2, q1 = ch1 & 3;

    f32x4 acc[4][4] = {};
    for (int kt = 0; kt < DSTATE; kt += 32) {
        __builtin_amdgcn_global_load_lds(
            (const __attribute__((address_space(1))) void*)&A[(size_t)(m0 + row0) * DSTATE + kt + q0 * 8],
            (__attribute__((address_space(3))) void*)&As[ch0 * 8 - lane * 8], 16, 0, 0);
        __builtin_amdgcn_global_load_lds(
            (const __attribute__((address_space(1))) void*)&A[(size_t)(m0 + row1) * DSTATE + kt + q1 * 8],
            (__attribute__((address_space(3))) void*)&As[ch1 * 8 - lane * 8], 16, 0, 0);
        __builtin_amdgcn_global_load_lds(
            (const __attribute__((address_space(1))) void*)&Bt[(size_t)(n0 + row0) * DSTATE + kt + q0 * 8],
            (__attribute__((address_space(3))) void*)&Bs[ch0 * 8 - lane * 8], 16, 0, 0);
        __builtin_amdgcn_global_load_lds(
            (const __attribute__((address_space(1))) void*)&Bt[(size_t)(n0 + row1) * DSTATE + kt + q1 * 8],
            (__attribute__((address_space(3))) void*)&Bs[ch1 * 8 - lane * 8], 16, 0, 0);
        __syncthreads();

        bf16x8 af[4], bf[4];
        #pragma unroll
        for (int f = 0; f < 4; ++f) {
            af[f] = *(const bf16x8*)&As[(wm * 64 + f * 16 + mr) * 32 + g * 8];
            bf[f] = *(const bf16x8*)&Bs[(wn * 64 + f * 16 + mr) * 32 + g * 8];
        }
        #pragma unroll
        for (int fm = 0; fm < 4; ++fm)
            #pragma unroll
            for (int fn = 0; fn < 4; ++fn)
                acc[fm][fn] = __builtin_amdgcn_mfma_f32_16x16x32_bf16(af[fm], bf[fn], acc[fm][fn], 0, 0, 0);
        __syncthreads();
    }
    #pragma unroll
    for (int fm = 0; fm < 4; ++fm) {
        #pragma unroll
        for (int fn = 0; fn < 4; ++fn) {
            int col = n0 + wn * 64 + fn * 16 + mr;
            if (col >= NCLS) continue;
            float bias = bo[col];
            #pragma unroll
            for (int r = 0; r < 4; ++r) {
                int row = m0 + wm * 64 + fm * 16 + g * 4 + r;
                C[(size_t)row * NCLS + col] = acc[fm][fn][r] + bias;
            }
        }
    }
}

// ---- softmax + loss ------------------------------------------------------
__device__ inline float wave_reduce_max(float v) {
    #pragma unroll
    for (int off = 32; off > 0; off >>= 1) v = fmaxf(v, __shfl_xor(v, off));
    return v;
}
__device__ inline float wave_reduce_sum(float v) {
    #pragma unroll
    for (int off = 32; off > 0; off >>= 1) v += __shfl_xor(v, off);
    return v;
}

// bf16-input softmax, 512 threads (8 waves) for full occupancy at 40KB LDS.
__launch_bounds__(512)
__global__ void softmax_loss_bf16(const unsigned short* __restrict__ Cb,  // [chunk][NCLS]
                                  const float* __restrict__ labels,       // chunk base
                                  float* __restrict__ probs,              // chunk base
                                  float* __restrict__ rowloss) {          // chunk base
    __shared__ float row[NCLS];          // 40 KB
    __shared__ float sm[8];
    const int tid = threadIdx.x;
    const size_t base = (size_t)blockIdx.x * NCLS;

    float m = -INFINITY;
    for (int c8 = tid; c8 < NCLS / 8; c8 += 512) {
        ushort4 u0 = *(const ushort4*)&Cb[base + c8 * 8];
        ushort4 u1 = *(const ushort4*)&Cb[base + c8 * 8 + 4];
        float v0 = b2f(u0.x), v1 = b2f(u0.y), v2 = b2f(u0.z), v3 = b2f(u0.w);
        float v4 = b2f(u1.x), v5 = b2f(u1.y), v6 = b2f(u1.z), v7 = b2f(u1.w);
        float4 a = {v0, v1, v2, v3}, b = {v4, v5, v6, v7};
        *(float4*)&row[c8 * 8] = a;
        *(float4*)&row[c8 * 8 + 4] = b;
        m = fmaxf(m, fmaxf(fmaxf(fmaxf(v0, v1), fmaxf(v2, v3)),
                           fmaxf(fmaxf(v4, v5), fmaxf(v6, v7))));
    }
    m = wave_reduce_max(m);
    if ((tid & 63) == 0) sm[tid >> 6] = m;
    __syncthreads();
    m = fmaxf(fmaxf(fmaxf(sm[0], sm[1]), fmaxf(sm[2], sm[3])),
              fmaxf(fmaxf(sm[4], sm[5]), fmaxf(sm[6], sm[7])));
    __syncthreads();

    float s = 0.f, dot = 0.f;
    for (int c4 = tid; c4 < NCLS / 4; c4 += 512) {
        float4 v = *(const float4*)&row[c4 * 4];
        float4 lb = *(const float4*)&labels[base + c4 * 4];
        s += expf(v.x - m) + expf(v.y - m) + expf(v.z - m) + expf(v.w - m);
        dot += lb.x * v.x + lb.y * v.y + lb.z * v.z + lb.w * v.w;
    }
    s = wave_reduce_sum(s);
    if ((tid & 63) == 0) sm[tid >> 6] = s;
    __syncthreads();
    s = ((sm[0] + sm[1]) + (sm[2] + sm[3])) + ((sm[4] + sm[5]) + (sm[6] + sm[7]));
    __syncthreads();
    dot = wave_reduce_sum(dot);
    if ((tid & 63) == 0) sm[tid >> 6] = dot;
    __syncthreads();
    dot = ((sm[0] + sm[1]) + (sm[2] + sm[3])) + ((sm[4] + sm[5]) + (sm[6] + sm[7]));

    float inv = 1.f / s;
    for (int c4 = tid; c4 < NCLS / 4; c4 += 512) {
        float4 v = *(const float4*)&row[c4 * 4];
        float4 o;
        o.x = expf(v.x - m) * inv; o.y = expf(v.y - m) * inv;
        o.z = expf(v.z - m) * inv; o.w = expf(v.w - m) * inv;
        *(float4*)&probs[base + c4 * 4] = o;
    }
    if (tid == 0) rowloss[blockIdx.x] = (m + logf(s)) - dot;
}

// f32 in-place softmax (fallback path)
__launch_bounds__(256)
__global__ void softmax_loss(float* __restrict__ logits,
                             const float* __restrict__ labels,
                             float* __restrict__ rowloss) {
    __shared__ float row[NCLS];
    __shared__ float sm[4];
    const int tid = threadIdx.x;
    const size_t base = (size_t)blockIdx.x * NCLS;

    float m = -INFINITY;
    for (int c4 = tid; c4 < NCLS / 4; c4 += 256) {
        float4 v = *(const float4*)&logits[base + c4 * 4];
        *(float4*)&row[c4 * 4] = v;
        m = fmaxf(fmaxf(m, fmaxf(v.x, v.y)), fmaxf(v.z, v.w));
    }
    m = wave_reduce_max(m);
    if ((tid & 63) == 0) sm[tid >> 6] = m;
    __syncthreads();
    m = fmaxf(fmaxf(sm[0], sm[1]), fmaxf(sm[2], sm[3]));
    __syncthreads();

    float s = 0.f, dot = 0.f;
    for (int c4 = tid; c4 < NCLS / 4; c4 += 256) {
        float4 v = *(const float4*)&row[c4 * 4];
        float4 lb = *(const float4*)&labels[base + c4 * 4];
        s += expf(v.x - m) + expf(v.y - m) + expf(v.z - m) + expf(v.w - m);
        dot += lb.x * v.x + lb.y * v.y + lb.z * v.z + lb.w * v.w;
    }
    s = wave_reduce_sum(s);
    if ((tid & 63) == 0) sm[tid >> 6] = s;
    __syncthreads();
    s = sm[0] + sm[1] + sm[2] + sm[3];
    __syncthreads();
    dot = wave_reduce_sum(dot);
    if ((tid & 63) == 0) sm[tid >> 6] = dot;
    __syncthreads();
    dot = sm[0] + sm[1] + sm[2] + sm[3];

    float inv = 1.f / s;
    for (int c4 = tid; c4 < NCLS / 4; c4 += 256) {
        float4 v = *(const float4*)&row[c4 * 4];
        float4 o;
        o.x = expf(v.x - m) * inv; o.y = expf(v.y - m) * inv;
        o.z = expf(v.z - m) * inv; o.w = expf(v.w - m) * inv;
        *(float4*)&logits[base + c4 * 4] = o;
    }
    if (tid == 0) rowloss[blockIdx.x] = (m + logf(s)) - dot;
}

__launch_bounds__(256)
__global__ void loss_reduce(const float* __restrict__ rowloss, float* __restrict__ out) {
    __shared__ float sm[4];
    float s = 0.f;
    for (int i = threadIdx.x; i < ROWS; i += 256) s += rowloss[i];
    s = wave_reduce_sum(s);
    if ((threadIdx.x & 63) == 0) sm[threadIdx.x >> 6] = s;
    __syncthreads();
    if (threadIdx.x == 0) out[0] = (sm[0] + sm[1] + sm[2] + sm[3]) * (1.f / ROWS);
}

// ---- launcher ------------------------------------------------------------
extern "C" void kernel_launch(void* const* d_in, const int* in_sizes, int n_in,
                              void* d_out, int out_size, void* d_ws, size_t ws_size,
                              hipStream_t stream) {
    const float* inputs = (const float*)d_in[0];
    const float* labels = (const float*)d_in[1];
    const float* c0     = (const float*)d_in[2];   // initial_state (cell)
    const float* h0     = (const float*)d_in[3];   // initial_output (hidden)
    const float* Wx     = (const float*)d_in[4];
    const float* Wh     = (const float*)d_in[5];
    const float* bias   = (const float*)d_in[6];
    const float* Wo     = (const float*)d_in[7];
    const float* bo     = (const float*)d_in[8];
    float* out = (float*)d_out;

    float* ws = (float*)d_ws;
    float* bp       = ws;                                  // 2048 f32
    float* rowloss  = bp + 2048;                           // 16384 f32
    unsigned short* WhT = (unsigned short*)(rowloss + 16384); // 2048*512
    unsigned short* WxT = WhT + 1048576;                   // 2048*256
    unsigned short* Xb  = WxT + 524288;                    // 16384*256
    unsigned short* h0b = Xb + 4194304;                    // 64*512
    unsigned short* hsb = h0b + 32768;                     // 16384*512
    unsigned short* WoT = hsb + 8388608;                   // 10112*512
    unsigned short* ZxT = WoT + 5177344;                   // 256*2048*64
    unsigned* bar = (unsigned*)(ZxT + 33554432);           // 1024 words (4 grp x 16 flags x 16 stride)
    unsigned short* Cb = (unsigned short*)(bar + 1024);    // CHUNK_ROWS*NCLS bf16

    size_t base_bytes = (size_t)((char*)Cb - (char*)d_ws);
    size_t need_bf16 = base_bytes + (size_t)CHUNK_ROWS * NCLS * sizeof(unsigned short);
    bool use_bf16 = (ws_size >= need_bf16);

    prep_all<<<11548, 256, 0, stream>>>(inputs, Wx, Wh, bias, h0, Wo,
                                        Xb, WxT, WhT, bp, h0b, bar, WoT);

    zx_gemm<<<dim3(T_STEPS, NGATE / 128), 256, 0, stream>>>(Xb, WxT, bp, ZxT);

    void* args[] = {(void*)&h0b, (void*)&c0, (void*)&WhT, (void*)&ZxT, (void*)&hsb, (void*)&bar};
    hipLaunchCooperativeKernel((const void*)lstm_scan_mfma, dim3(SCAN_BLOCKS), dim3(256),
                               args, 0, stream);

    if (use_bf16) {
        for (int row0 = 0; row0 < ROWS; row0 += CHUNK_ROWS) {
            gemm_logits_bf16<<<dim3(NCLS_PAD / 128, CHUNK_ROWS / 128), 256, 0, stream>>>(
                hsb + (size_t)row0 * DSTATE, WoT, bo, Cb);
            softmax_loss_bf16<<<CHUNK_ROWS, 512, 0, stream>>>(
                Cb, labels + (size_t)row0 * NCLS, out + (size_t)row0 * NCLS, rowloss + row0);
        }
    } else {
        gemm_logits_mfma<<<dim3(NCLS_PAD / 128, ROWS / 128), 256, 0, stream>>>(hsb, WoT, bo, out);
        softmax_loss<<<ROWS, 256, 0, stream>>>(out, labels, rowloss);
    }
    loss_reduce<<<1, 256, 0, stream>>>(rowloss, out + (size_t)ROWS * NCLS);
}